// Round 9
// baseline (144.737 us; speedup 1.0000x reference)
//
#include <hip/hip_runtime.h>
#include <hip/hip_fp16.h>
#include <math.h>

#define C_DIM 256
#define H_DIM 8
#define L_DIM 4
#define P_DIM 4
#define LQ 5440
#define LEN_IN 5440
#define NB 4
#define M_ROWS (NB * LQ)       // 21760
#define NPANEL (M_ROWS / 128)  // 170 row-panels

typedef __attribute__((ext_vector_type(8))) _Float16 f16x8;
typedef __attribute__((ext_vector_type(8))) unsigned short u16x8;
typedef __attribute__((ext_vector_type(4))) float f32x4;

__device__ __forceinline__ void split_f32(float a, __half& h, __half& l) {
    h = __float2half(a);
    l = __float2half(a - __half2float(h));
}

// ---- all weight splits + bias concat in ONE kernel ----
__global__ __launch_bounds__(256) void convert_all(const float* __restrict__ w_val,
                                                   const float* __restrict__ w_off,
                                                   const float* __restrict__ w_attn,
                                                   const float* __restrict__ w_out,
                                                   const float* __restrict__ b_off,
                                                   const float* __restrict__ b_attn,
                                                   __half* __restrict__ wv_hi, __half* __restrict__ wv_lo,
                                                   __half* __restrict__ wc_hi, __half* __restrict__ wc_lo,
                                                   __half* __restrict__ wt_hi, __half* __restrict__ wt_lo,
                                                   float* __restrict__ bc) {
    const int b = blockIdx.x, k = threadIdx.x;
    if (b < 896) {
        const float* w; __half *hi, *lo; int ncols, col, orow;
        if (b < 256)      { w = w_val;  hi = wv_hi; lo = wv_lo; ncols = 256; col = b;       orow = col; }
        else if (b < 512) { w = w_off;  hi = wc_hi; lo = wc_lo; ncols = 256; col = b - 256; orow = col; }
        else if (b < 640) { w = w_attn; hi = wc_hi; lo = wc_lo; ncols = 128; col = b - 512; orow = col + 256; }
        else              { w = w_out;  hi = wt_hi; lo = wt_lo; ncols = 256; col = b - 640; orow = col; }
        const float a = w[(size_t)k * ncols + col];
        __half h, l;
        split_f32(a, h, l);
        hi[(size_t)orow * 256 + k] = h;
        lo[(size_t)orow * 256 + k] = l;
    } else if (b == 896) {
        bc[k] = b_off[k];
    } else {
        if (k < 128) bc[256 + k] = b_attn[k];
    }
}

// ------- Fused runtime f16x3 MFMA GEMM: out[M x NC] = A[M x 256] @ W^T + bias -------
// TWO independent GEMMs in one dispatch (block-uniform select on bid vs split):
// better machine fill than serial launches (1700 blocks ~ 6.6/CU vs 2.7 + 2.0).
// Geometry fixed: BM=128, BN=64, BK=32, 256 thr = 2x2 waves, wave tile 64x32
// (4x2 frags of 16x16x32). A fp32, hi/lo split INLINE during staging; W pre-split
// TRANSPOSED [NC][256] (row stride 256 regardless of NC). fp32 emulated as
// Ahi*Bhi + Alo*Bhi + Ahi*Blo (3 MFMA, same order as prior rounds -> bit-identical).
// LDS [comp][row][32] halfs, XOR chunk swizzle on 16B chunks. 24KB LDS.
__global__ __launch_bounds__(256, 4) void gemm_f16x3(
    int split,
    const float* __restrict__ A0, const __half* __restrict__ B0h, const __half* __restrict__ B0l,
    const float* __restrict__ bias0, float* __restrict__ out0, int NC0,
    const float* __restrict__ A1, const __half* __restrict__ B1h, const __half* __restrict__ B1l,
    const float* __restrict__ bias1, float* __restrict__ out1, int NC1) {
    __shared__ __align__(16) __half sA[2][128][32];
    __shared__ __align__(16) __half sB[2][64][32];

    const int bid = blockIdx.x;
    const float* A; const __half* Bhi; const __half* Blo;
    const float* bias; float* outp; int NC, idx;
    if (bid < split) { A = A0; Bhi = B0h; Blo = B0l; bias = bias0; outp = out0; NC = NC0; idx = bid; }
    else             { A = A1; Bhi = B1h; Blo = B1l; bias = bias1; outp = out1; NC = NC1; idx = bid - split; }
    const int NX = NC >> 6;          // column tiles per panel
    const int y = idx / NX;          // row panel (runtime div, once per block)
    const int x = idx - y * NX;

    const int n0 = x * 64;
    const int row0 = y * 128;
    const int t = threadIdx.x;
    const int w = t >> 6, lane = t & 63;
    const int bm = (w >> 1) * 64, bn = (w & 1) * 32;
    const int fr = lane & 15;   // frag row (A) / col (B) / col (C)
    const int fc = lane >> 4;   // frag k-chunk (0..3); C row group

    // A: 512 8-float chunks per tile; thread t handles chunks t, t+256
    const int ar1 = t >> 2, ar2 = ar1 + 64;
    const int ak8 = t & 3;
    const int asw1 = (ak8 ^ ((ar1 >> 1) & 3)) * 8;
    const int asw2 = (ak8 ^ ((ar2 >> 1) & 3)) * 8;
    // B: 256 16B chunks per comp; one per thread
    const int br = t >> 2;
    const int bc8 = t & 3;
    const int bsw = (bc8 ^ ((br >> 1) & 3)) * 8;

    const size_t ga1 = (size_t)(row0 + ar1) * 256 + ak8 * 8;   // fp32 floats
    const size_t ga2 = (size_t)(row0 + ar2) * 256 + ak8 * 8;
    const size_t gb  = (size_t)(n0 + br) * 256 + bc8 * 8;      // f16 halfs

    f32x4 acc[4][2];
#pragma unroll
    for (int m = 0; m < 4; ++m)
#pragma unroll
        for (int n = 0; n < 2; ++n)
#pragma unroll
            for (int r = 0; r < 4; ++r) acc[m][n][r] = 0.f;

    float4 pa[4];
    float4 pb[2];
    pa[0] = *(const float4*)(A + ga1);
    pa[1] = *(const float4*)(A + ga1 + 4);
    pa[2] = *(const float4*)(A + ga2);
    pa[3] = *(const float4*)(A + ga2 + 4);
    pb[0] = *(const float4*)(Bhi + gb);
    pb[1] = *(const float4*)(Blo + gb);

    for (int kt = 0; kt < 8; ++kt) {
        if (kt) __syncthreads();
        // inline split of the two A chunks
#pragma unroll
        for (int ch = 0; ch < 2; ++ch) {
            const float4 u = pa[2 * ch], v = pa[2 * ch + 1];
            const float e[8] = {u.x, u.y, u.z, u.w, v.x, v.y, v.z, v.w};
            u16x8 Hh, Ll;
#pragma unroll
            for (int i = 0; i < 8; ++i) {
                __half h, l;
                split_f32(e[i], h, l);
                Hh[i] = __half_as_ushort(h);
                Ll[i] = __half_as_ushort(l);
            }
            const int row = ch ? ar2 : ar1;
            const int sw = ch ? asw2 : asw1;
            *(u16x8*)&sA[0][row][sw] = Hh;
            *(u16x8*)&sA[1][row][sw] = Ll;
        }
        *(float4*)&sB[0][br][bsw] = pb[0];
        *(float4*)&sB[1][br][bsw] = pb[1];
        __syncthreads();
        if (kt < 7) {
            const size_t ko = (size_t)(kt + 1) * 32;
            pa[0] = *(const float4*)(A + ga1 + ko);
            pa[1] = *(const float4*)(A + ga1 + ko + 4);
            pa[2] = *(const float4*)(A + ga2 + ko);
            pa[3] = *(const float4*)(A + ga2 + ko + 4);
            pb[0] = *(const float4*)(Bhi + gb + ko);
            pb[1] = *(const float4*)(Blo + gb + ko);
        }

        f16x8 bhf[2], blf[2];
#pragma unroll
        for (int n = 0; n < 2; ++n) {
            const int rowb = bn + n * 16 + fr;
            const int swb = (fc ^ ((rowb >> 1) & 3)) * 8;
            bhf[n] = *(const f16x8*)&sB[0][rowb][swb];
            blf[n] = *(const f16x8*)&sB[1][rowb][swb];
        }
#pragma unroll
        for (int m = 0; m < 4; ++m) {
            const int rowa = bm + m * 16 + fr;
            const int swa = (fc ^ ((rowa >> 1) & 3)) * 8;
            const f16x8 ah = *(const f16x8*)&sA[0][rowa][swa];
            const f16x8 al = *(const f16x8*)&sA[1][rowa][swa];
#pragma unroll
            for (int n = 0; n < 2; ++n) {
                acc[m][n] = __builtin_amdgcn_mfma_f32_16x16x32_f16(ah, bhf[n], acc[m][n], 0, 0, 0);
                acc[m][n] = __builtin_amdgcn_mfma_f32_16x16x32_f16(al, bhf[n], acc[m][n], 0, 0, 0);
                acc[m][n] = __builtin_amdgcn_mfma_f32_16x16x32_f16(ah, blf[n], acc[m][n], 0, 0, 0);
            }
        }
    }

    // epilogue: C/D layout col = lane&15, row = (lane>>4)*4 + reg
#pragma unroll
    for (int n = 0; n < 2; ++n) {
        const int col = n0 + bn + n * 16 + fr;
        const float bv = bias[col];
#pragma unroll
        for (int m = 0; m < 4; ++m) {
            const int row = row0 + bm + m * 16 + fc * 4;
#pragma unroll
            for (int r = 0; r < 4; ++r)
                outp[(size_t)(row + r) * NC + col] = acc[m][n][r] + bv;
        }
    }
}

// ---------------- Sampling: softmax + bilinear gather + weighted sum ----------------
// 256 threads = 4 waves; wave processes 2 queries sequentially, private LDS slice,
// no barrier. XCD batch affinity (bid&7 ~ xcd): XCD pair {2n,2n+1} handles only
// batch n -> value slice (5.6 MB) is L2-resident. Gather loop batches 2 lp
// iterations (8 dwordx4 in flight). LDS perm p = lp*8+(h^(lp&7)): conflict-free.
__global__ __launch_bounds__(256) void sample_kernel(const float* __restrict__ value,   // [N*LEN_IN, C]
                                                     const float* __restrict__ ol,      // [N*LQ, 384]
                                                     const float* __restrict__ refpts,  // [N, LQ, L, 2]
                                                     float* __restrict__ tmp) {         // [N*LQ, C]
    const int t = threadIdx.x;
    const int w = t >> 6, lane = t & 63;

    __shared__ __align__(16) float4 s_aw[4][128];
    __shared__ __align__(16) uint4 s_of[4][128];

    const int h = lane >> 3;
    const unsigned l16 = (unsigned)(lane * 16);

    const int bid = blockIdx.x;            // 0..2719
    const int xcd = bid & 7;
    const int pos = bid >> 3;              // 0..339
    const int n = xcd >> 1;                // batch handled by this XCD pair
    const int qgrp = (xcd & 1) * 340 + pos;

    const char* vbn = (const char*)value + (size_t)n * (LEN_IN * C_DIM * 4);  // wave-uniform

    for (int it = 0; it < 2; ++it) {
        const int q = n * LQ + qgrp * 8 + w * 2 + it;

#pragma unroll
        for (int s = 0; s < 2; ++s) {
            const int j = lane + 64 * s;     // slot = hq*16 + lp, lp = (l<<2)|p
            const int hq = j >> 4, lp = j & 15;
            const int l = lp >> 2;
            const int ww = 64 >> l;
            int st = 0;
            if (l == 1) st = 4096;
            else if (l == 2) st = 5120;
            else if (l == 3) st = 5376;

            const float2 oxy = *(const float2*)&ol[(size_t)q * 384 + 2 * j];
            const float2 rxy = *(const float2*)&refpts[((size_t)q * L_DIM + l) * 2];

            const float fw = (float)ww;
            const float x = fminf(fmaxf(rxy.x + oxy.x, 0.f), 1.f) * fw - 0.5f;
            const float y = fminf(fmaxf(rxy.y + oxy.y, 0.f), 1.f) * fw - 0.5f;
            const int xi = (int)floorf(x);
            const int yi = (int)floorf(y);
            const int x0i = min(max(xi, 0), ww - 1);
            const int x1i = min(max(xi + 1, 0), ww - 1);
            const int y0i = min(max(yi, 0), ww - 1);
            const int y1i = min(max(yi + 1, 0), ww - 1);
            const float wx0 = (float)x1i - x, wx1 = x - (float)x0i;
            const float wy0 = (float)y1i - y, wy1 = y - (float)y0i;

            const float lg = ol[(size_t)q * 384 + 256 + j];
            float m = lg;
#pragma unroll
            for (int o = 8; o; o >>= 1) m = fmaxf(m, __shfl_xor(m, o, 16));
            const float e = expf(lg - m);
            float sm = e;
#pragma unroll
            for (int o = 8; o; o >>= 1) sm += __shfl_xor(sm, o, 16);
            const float a = e / sm;

            const int p = lp * 8 + (hq ^ (lp & 7));
            float4 aw;
            aw.x = a * (wx0 * wy0);   // (y0,x0)
            aw.y = a * (wx0 * wy1);   // (y1,x0)
            aw.z = a * (wx1 * wy0);   // (y0,x1)
            aw.w = a * (wx1 * wy1);   // (y1,x1)
            uint4 of;
            of.x = (unsigned)(st + y0i * ww + x0i) << 10;   // row byte offset
            of.y = (unsigned)(st + y1i * ww + x0i) << 10;
            of.z = (unsigned)(st + y0i * ww + x1i) << 10;
            of.w = (unsigned)(st + y1i * ww + x1i) << 10;
            s_aw[w][p] = aw;
            s_of[w][p] = of;
        }
        // no barrier: same-wave LDS write->read ordered by lgkmcnt

        float4 acc;
        acc.x = 0.f; acc.y = 0.f; acc.z = 0.f; acc.w = 0.f;
#pragma unroll
        for (int lp = 0; lp < 16; lp += 2) {
            const int p0 = lp * 8 + (h ^ (lp & 7));
            const int p1 = (lp + 1) * 8 + (h ^ ((lp + 1) & 7));
            const float4 aw0 = s_aw[w][p0];
            const uint4 of0 = s_of[w][p0];
            const float4 aw1 = s_aw[w][p1];
            const uint4 of1 = s_of[w][p1];
            const float4 v0 = *(const float4*)(vbn + (of0.x + l16));
            const float4 v1 = *(const float4*)(vbn + (of0.y + l16));
            const float4 v2 = *(const float4*)(vbn + (of0.z + l16));
            const float4 v3 = *(const float4*)(vbn + (of0.w + l16));
            const float4 u0 = *(const float4*)(vbn + (of1.x + l16));
            const float4 u1 = *(const float4*)(vbn + (of1.y + l16));
            const float4 u2 = *(const float4*)(vbn + (of1.z + l16));
            const float4 u3 = *(const float4*)(vbn + (of1.w + l16));
            acc.x += aw0.x * v0.x + aw0.y * v1.x + aw0.z * v2.x + aw0.w * v3.x;
            acc.y += aw0.x * v0.y + aw0.y * v1.y + aw0.z * v2.y + aw0.w * v3.y;
            acc.z += aw0.x * v0.z + aw0.y * v1.z + aw0.z * v2.z + aw0.w * v3.z;
            acc.w += aw0.x * v0.w + aw0.y * v1.w + aw0.z * v2.w + aw0.w * v3.w;
            acc.x += aw1.x * u0.x + aw1.y * u1.x + aw1.z * u2.x + aw1.w * u3.x;
            acc.y += aw1.x * u0.y + aw1.y * u1.y + aw1.z * u2.y + aw1.w * u3.y;
            acc.z += aw1.x * u0.z + aw1.y * u1.z + aw1.z * u2.z + aw1.w * u3.z;
            acc.w += aw1.x * u0.w + aw1.y * u1.w + aw1.z * u2.w + aw1.w * u3.w;
        }
        *(float4*)&tmp[(size_t)q * 256 + (size_t)(lane * 4)] = acc;
    }
}

extern "C" void kernel_launch(void* const* d_in, const int* in_sizes, int n_in,
                              void* d_out, int out_size, void* d_ws, size_t ws_size,
                              hipStream_t stream) {
    const float* query         = (const float*)d_in[0];
    const float* refpts        = (const float*)d_in[1];
    const float* input_flatten = (const float*)d_in[2];
    // d_in[3] = input_spatial_shapes, d_in[4] = input_level_start_index (static, hardcoded)
    const float* w_off  = (const float*)d_in[5];
    const float* b_off  = (const float*)d_in[6];
    const float* w_attn = (const float*)d_in[7];
    const float* b_attn = (const float*)d_in[8];
    const float* w_val  = (const float*)d_in[9];
    const float* b_val  = (const float*)d_in[10];
    const float* w_out  = (const float*)d_in[11];
    const float* b_out  = (const float*)d_in[12];
    float* out = (float*)d_out;

    const size_t nr = (size_t)M_ROWS;            // 21760
    float* p = (float*)d_ws;
    float* value_ws = p; p += nr * 256;          // fp32 [M,256]
    float* ol_ws    = p; p += nr * 384;          // fp32 [M,384] = [offv | logits]
    float* tmp_ws   = p; p += nr * 256;          // fp32 [M,256]
    float* bc_ws    = p; p += 384;               // concat bias [b_off | b_attn]
    __half* wv_hi = (__half*)p;                  // weights hi/lo, transposed [NC][256]
    __half* wv_lo = wv_hi + 256 * 256;
    __half* wc_hi = wv_lo + 256 * 256;           // combined [384][256]
    __half* wc_lo = wc_hi + 384 * 256;
    __half* wt_hi = wc_lo + 384 * 256;
    __half* wt_lo = wt_hi + 256 * 256;

    convert_all<<<898, 256, 0, stream>>>(w_val, w_off, w_attn, w_out, b_off, b_attn,
                                         wv_hi, wv_lo, wc_hi, wc_lo, wt_hi, wt_lo, bc_ws);

    const int GV = NPANEL * 4;   // 680  (NC=256, BN=64)
    const int GO = NPANEL * 6;   // 1020 (NC=384, BN=64)

    // fused: value GEMM + offset/logit GEMM in one dispatch (6.6 blocks/CU fill)
    gemm_f16x3<<<GV + GO, 256, 0, stream>>>(GV,
        input_flatten, wv_hi, wv_lo, b_val, value_ws, 256,
        query, wc_hi, wc_lo, bc_ws, ol_ws, 384);

    sample_kernel<<<M_ROWS / 8, 256, 0, stream>>>(value_ws, ol_ws, refpts, tmp_ws);

    gemm_f16x3<<<GV, 256, 0, stream>>>(GV,
        tmp_ws, wt_hi, wt_lo, b_out, out, 256,
        tmp_ws, wt_hi, wt_lo, b_out, out, 256);
}

// Round 10
// 138.612 us; speedup vs baseline: 1.0442x; 1.0442x over previous
//
#include <hip/hip_runtime.h>
#include <hip/hip_fp16.h>
#include <math.h>

#define C_DIM 256
#define H_DIM 8
#define L_DIM 4
#define P_DIM 4
#define LQ 5440
#define LEN_IN 5440
#define NB 4
#define M_ROWS (NB * LQ)       // 21760
#define NPANEL (M_ROWS / 128)  // 170 row-panels

typedef __attribute__((ext_vector_type(8))) _Float16 f16x8;
typedef __attribute__((ext_vector_type(8))) unsigned short u16x8;
typedef __attribute__((ext_vector_type(4))) float f32x4;

__device__ __forceinline__ void split_f32(float a, __half& h, __half& l) {
    h = __float2half(a);
    l = __float2half(a - __half2float(h));
}

// ---- all weight splits + bias concat in ONE kernel ----
__global__ __launch_bounds__(256) void convert_all(const float* __restrict__ w_val,
                                                   const float* __restrict__ w_off,
                                                   const float* __restrict__ w_attn,
                                                   const float* __restrict__ w_out,
                                                   const float* __restrict__ b_off,
                                                   const float* __restrict__ b_attn,
                                                   __half* __restrict__ wv_hi, __half* __restrict__ wv_lo,
                                                   __half* __restrict__ wc_hi, __half* __restrict__ wc_lo,
                                                   __half* __restrict__ wt_hi, __half* __restrict__ wt_lo,
                                                   float* __restrict__ bc) {
    const int b = blockIdx.x, k = threadIdx.x;
    if (b < 896) {
        const float* w; __half *hi, *lo; int ncols, col, orow;
        if (b < 256)      { w = w_val;  hi = wv_hi; lo = wv_lo; ncols = 256; col = b;       orow = col; }
        else if (b < 512) { w = w_off;  hi = wc_hi; lo = wc_lo; ncols = 256; col = b - 256; orow = col; }
        else if (b < 640) { w = w_attn; hi = wc_hi; lo = wc_lo; ncols = 128; col = b - 512; orow = col + 256; }
        else              { w = w_out;  hi = wt_hi; lo = wt_lo; ncols = 256; col = b - 640; orow = col; }
        const float a = w[(size_t)k * ncols + col];
        __half h, l;
        split_f32(a, h, l);
        hi[(size_t)orow * 256 + k] = h;
        lo[(size_t)orow * 256 + k] = l;
    } else if (b == 896) {
        bc[k] = b_off[k];
    } else {
        if (k < 128) bc[256 + k] = b_attn[k];
    }
}

// ---------------- f16x3 MFMA GEMM: out[M x NC] = A[M x 256] @ W^T + bias ------------
// A is fp32 [M][256]; hi/lo split INLINE during LDS staging. W pre-split hi/lo f16,
// TRANSPOSED [NC][256]. BM=128, BN template, BK=32, 256 threads = 2x2 waves.
// fp32 emulated as Ahi*Bhi + Alo*Bhi + Ahi*Blo (3 MFMA per frag).
// COALESCED EPILOGUE (new): per-wave LDS staging [16][BN/2] f32 with chunk-XOR
// swizzle, then float4 stores where each 8-lane group writes one FULL 128B line.
// Fixes the 2.4x write amplification (partial-line RMW) the scalar epilogue caused.
template <int NC, int BN, int MINW>
__global__ __launch_bounds__(256, MINW) void gemm_f16x3(const float* __restrict__ A,
                                                        const __half* __restrict__ Bhi,
                                                        const __half* __restrict__ Blo,
                                                        const float* __restrict__ bias,
                                                        float* __restrict__ outp) {
    constexpr int NF = BN / 32;      // B frags per wave
    constexpr int BCH = BN / 64;     // B staging chunks per thread per comp
    constexpr int WC = BN / 2;       // per-wave output cols
    constexpr int NCH = WC / 4;      // float4 chunks per epi row (8 or 16)

    __shared__ __align__(16) __half sA[2][128][32];
    __shared__ __align__(16) __half sB[2][BN][32];
    __shared__ __align__(16) float sepi[4][16][WC];   // per-wave epilogue buffer

    const int n0 = blockIdx.x * BN;
    const int row0 = blockIdx.y * 128;
    const int t = threadIdx.x;
    const int w = t >> 6, lane = t & 63;
    const int bm = (w >> 1) * 64, bn = (w & 1) * WC;
    const int fr = lane & 15;   // frag row (A) / col (B) / col (C)
    const int fc = lane >> 4;   // frag k-chunk (0..3); C row group

    // A: 512 8-float chunks per tile; thread t handles chunks t, t+256
    const int ar1 = t >> 2, ar2 = ar1 + 64;
    const int ak8 = t & 3;
    const int asw1 = (ak8 ^ ((ar1 >> 1) & 3)) * 8;
    const int asw2 = (ak8 ^ ((ar2 >> 1) & 3)) * 8;
    // B: BN*4 16B chunks per comp
    const int bc8 = t & 3;
    int brr[BCH], bsw[BCH];
#pragma unroll
    for (int cc = 0; cc < BCH; ++cc) {
        brr[cc] = (t >> 2) + 64 * cc;
        bsw[cc] = (bc8 ^ ((brr[cc] >> 1) & 3)) * 8;
    }

    const size_t ga1 = (size_t)(row0 + ar1) * 256 + ak8 * 8;   // fp32 floats
    const size_t ga2 = (size_t)(row0 + ar2) * 256 + ak8 * 8;
    size_t gb[BCH];
#pragma unroll
    for (int cc = 0; cc < BCH; ++cc) gb[cc] = (size_t)(n0 + brr[cc]) * 256 + bc8 * 8;

    f32x4 acc[4][NF];
#pragma unroll
    for (int m = 0; m < 4; ++m)
#pragma unroll
        for (int n = 0; n < NF; ++n)
#pragma unroll
            for (int r = 0; r < 4; ++r) acc[m][n][r] = 0.f;

    float4 pa[4];
    float4 pb[2 * BCH];
    pa[0] = *(const float4*)(A + ga1);
    pa[1] = *(const float4*)(A + ga1 + 4);
    pa[2] = *(const float4*)(A + ga2);
    pa[3] = *(const float4*)(A + ga2 + 4);
#pragma unroll
    for (int cc = 0; cc < BCH; ++cc) {
        pb[cc] = *(const float4*)(Bhi + gb[cc]);
        pb[BCH + cc] = *(const float4*)(Blo + gb[cc]);
    }

    for (int kt = 0; kt < 8; ++kt) {
        if (kt) __syncthreads();
        // inline split of the two A chunks
#pragma unroll
        for (int ch = 0; ch < 2; ++ch) {
            const float4 u = pa[2 * ch], v = pa[2 * ch + 1];
            const float e[8] = {u.x, u.y, u.z, u.w, v.x, v.y, v.z, v.w};
            u16x8 Hh, Ll;
#pragma unroll
            for (int i = 0; i < 8; ++i) {
                __half h, l;
                split_f32(e[i], h, l);
                Hh[i] = __half_as_ushort(h);
                Ll[i] = __half_as_ushort(l);
            }
            const int row = ch ? ar2 : ar1;
            const int sw = ch ? asw2 : asw1;
            *(u16x8*)&sA[0][row][sw] = Hh;
            *(u16x8*)&sA[1][row][sw] = Ll;
        }
#pragma unroll
        for (int cc = 0; cc < BCH; ++cc) {
            *(float4*)&sB[0][brr[cc]][bsw[cc]] = pb[cc];
            *(float4*)&sB[1][brr[cc]][bsw[cc]] = pb[BCH + cc];
        }
        __syncthreads();
        if (kt < 7) {
            const size_t ko = (size_t)(kt + 1) * 32;
            pa[0] = *(const float4*)(A + ga1 + ko);
            pa[1] = *(const float4*)(A + ga1 + ko + 4);
            pa[2] = *(const float4*)(A + ga2 + ko);
            pa[3] = *(const float4*)(A + ga2 + ko + 4);
#pragma unroll
            for (int cc = 0; cc < BCH; ++cc) {
                pb[cc] = *(const float4*)(Bhi + gb[cc] + ko);
                pb[BCH + cc] = *(const float4*)(Blo + gb[cc] + ko);
            }
        }

        f16x8 bhf[NF], blf[NF];
#pragma unroll
        for (int n = 0; n < NF; ++n) {
            const int rowb = bn + n * 16 + fr;
            const int swb = (fc ^ ((rowb >> 1) & 3)) * 8;
            bhf[n] = *(const f16x8*)&sB[0][rowb][swb];
            blf[n] = *(const f16x8*)&sB[1][rowb][swb];
        }
#pragma unroll
        for (int m = 0; m < 4; ++m) {
            const int rowa = bm + m * 16 + fr;
            const int swa = (fc ^ ((rowa >> 1) & 3)) * 8;
            const f16x8 ah = *(const f16x8*)&sA[0][rowa][swa];
            const f16x8 al = *(const f16x8*)&sA[1][rowa][swa];
#pragma unroll
            for (int n = 0; n < NF; ++n) {
                acc[m][n] = __builtin_amdgcn_mfma_f32_16x16x32_f16(ah, bhf[n], acc[m][n], 0, 0, 0);
                acc[m][n] = __builtin_amdgcn_mfma_f32_16x16x32_f16(al, bhf[n], acc[m][n], 0, 0, 0);
                acc[m][n] = __builtin_amdgcn_mfma_f32_16x16x32_f16(ah, blf[n], acc[m][n], 0, 0, 0);
            }
        }
    }

    // ---- coalesced epilogue: C/D frag layout col = lane&15, row = (lane>>4)*4+reg
    // stage per-wave into sepi (chunk ^ (row&7) swizzle: conflict-free writes,
    // floor-rate b128 reads), then full-line float4 stores.
    float bv[NF];
#pragma unroll
    for (int n = 0; n < NF; ++n) bv[n] = bias[n0 + bn + n * 16 + fr];

#pragma unroll
    for (int m = 0; m < 4; ++m) {
#pragma unroll
        for (int n = 0; n < NF; ++n) {
            const int kch = n * 4 + (fr >> 2);   // float4 chunk within epi row
            const int lo4 = fr & 3;
#pragma unroll
            for (int r = 0; r < 4; ++r) {
                const int rw = fc * 4 + r;
                const int sk = (kch ^ (rw & 7)) & (NCH - 1);
                sepi[w][rw][sk * 4 + lo4] = acc[m][n][r] + bv[n];
            }
        }
        // same-wave ds ordering (lgkmcnt) -- no barrier needed, buffer is private
#pragma unroll
        for (int jj = 0; jj < NF; ++jj) {       // NF rounds of 64 float4
            const int flat = jj * 64 + lane;
            const int rw = flat / NCH;
            const int k = flat % NCH;
            const int sk = (k ^ (rw & 7)) & (NCH - 1);
            const float4 vv = *(const float4*)&sepi[w][rw][sk * 4];
            const int grow = row0 + bm + m * 16 + rw;
            *(float4*)&outp[(size_t)grow * NC + (n0 + bn + k * 4)] = vv;
        }
    }
}

// ---------------- Sampling: softmax + bilinear gather + weighted sum ----------------
// 256 threads = 4 waves; wave processes 2 queries sequentially, private LDS slice,
// no barrier. XCD batch affinity (bid&7 ~ xcd): XCD pair {2n,2n+1} handles only
// batch n -> value slice (5.6 MB) is L2-resident. Gathers: wave-uniform base +
// 32-bit offsets, 128B coalesced. LDS perm p = lp*8+(h^(lp&7)): conflict-free.
__global__ __launch_bounds__(256) void sample_kernel(const float* __restrict__ value,   // [N*LEN_IN, C]
                                                     const float* __restrict__ ol,      // [N*LQ, 384]
                                                     const float* __restrict__ refpts,  // [N, LQ, L, 2]
                                                     float* __restrict__ tmp) {         // [N*LQ, C]
    const int t = threadIdx.x;
    const int w = t >> 6, lane = t & 63;

    __shared__ __align__(16) float4 s_aw[4][128];
    __shared__ __align__(16) uint4 s_of[4][128];

    const int h = lane >> 3;
    const unsigned l16 = (unsigned)(lane * 16);

    const int bid = blockIdx.x;            // 0..2719
    const int xcd = bid & 7;
    const int pos = bid >> 3;              // 0..339
    const int n = xcd >> 1;                // batch handled by this XCD pair
    const int qgrp = (xcd & 1) * 340 + pos;

    const char* vbn = (const char*)value + (size_t)n * (LEN_IN * C_DIM * 4);  // wave-uniform

    for (int it = 0; it < 2; ++it) {
        const int q = n * LQ + qgrp * 8 + w * 2 + it;

#pragma unroll
        for (int s = 0; s < 2; ++s) {
            const int j = lane + 64 * s;     // slot = hq*16 + lp, lp = (l<<2)|p
            const int hq = j >> 4, lp = j & 15;
            const int l = lp >> 2;
            const int ww = 64 >> l;
            int st = 0;
            if (l == 1) st = 4096;
            else if (l == 2) st = 5120;
            else if (l == 3) st = 5376;

            const float2 oxy = *(const float2*)&ol[(size_t)q * 384 + 2 * j];
            const float2 rxy = *(const float2*)&refpts[((size_t)q * L_DIM + l) * 2];

            const float fw = (float)ww;
            const float x = fminf(fmaxf(rxy.x + oxy.x, 0.f), 1.f) * fw - 0.5f;
            const float y = fminf(fmaxf(rxy.y + oxy.y, 0.f), 1.f) * fw - 0.5f;
            const int xi = (int)floorf(x);
            const int yi = (int)floorf(y);
            const int x0i = min(max(xi, 0), ww - 1);
            const int x1i = min(max(xi + 1, 0), ww - 1);
            const int y0i = min(max(yi, 0), ww - 1);
            const int y1i = min(max(yi + 1, 0), ww - 1);
            const float wx0 = (float)x1i - x, wx1 = x - (float)x0i;
            const float wy0 = (float)y1i - y, wy1 = y - (float)y0i;

            const float lg = ol[(size_t)q * 384 + 256 + j];
            float m = lg;
#pragma unroll
            for (int o = 8; o; o >>= 1) m = fmaxf(m, __shfl_xor(m, o, 16));
            const float e = expf(lg - m);
            float sm = e;
#pragma unroll
            for (int o = 8; o; o >>= 1) sm += __shfl_xor(sm, o, 16);
            const float a = e / sm;

            const int p = lp * 8 + (hq ^ (lp & 7));
            float4 aw;
            aw.x = a * (wx0 * wy0);   // (y0,x0)
            aw.y = a * (wx0 * wy1);   // (y1,x0)
            aw.z = a * (wx1 * wy0);   // (y0,x1)
            aw.w = a * (wx1 * wy1);   // (y1,x1)
            uint4 of;
            of.x = (unsigned)(st + y0i * ww + x0i) << 10;   // row byte offset
            of.y = (unsigned)(st + y1i * ww + x0i) << 10;
            of.z = (unsigned)(st + y0i * ww + x1i) << 10;
            of.w = (unsigned)(st + y1i * ww + x1i) << 10;
            s_aw[w][p] = aw;
            s_of[w][p] = of;
        }
        // no barrier: same-wave LDS write->read ordered by lgkmcnt

        float4 acc;
        acc.x = 0.f; acc.y = 0.f; acc.z = 0.f; acc.w = 0.f;
#pragma unroll
        for (int lp = 0; lp < 16; ++lp) {
            const int p = lp * 8 + (h ^ (lp & 7));
            const float4 aw = s_aw[w][p];
            const uint4 of = s_of[w][p];
            const float4 v0 = *(const float4*)(vbn + (of.x + l16));
            const float4 v1 = *(const float4*)(vbn + (of.y + l16));
            const float4 v2 = *(const float4*)(vbn + (of.z + l16));
            const float4 v3 = *(const float4*)(vbn + (of.w + l16));
            acc.x += aw.x * v0.x + aw.y * v1.x + aw.z * v2.x + aw.w * v3.x;
            acc.y += aw.x * v0.y + aw.y * v1.y + aw.z * v2.y + aw.w * v3.y;
            acc.z += aw.x * v0.z + aw.y * v1.z + aw.z * v2.z + aw.w * v3.z;
            acc.w += aw.x * v0.w + aw.y * v1.w + aw.z * v2.w + aw.w * v3.w;
        }
        *(float4*)&tmp[(size_t)q * 256 + (size_t)(lane * 4)] = acc;
    }
}

extern "C" void kernel_launch(void* const* d_in, const int* in_sizes, int n_in,
                              void* d_out, int out_size, void* d_ws, size_t ws_size,
                              hipStream_t stream) {
    const float* query         = (const float*)d_in[0];
    const float* refpts        = (const float*)d_in[1];
    const float* input_flatten = (const float*)d_in[2];
    // d_in[3] = input_spatial_shapes, d_in[4] = input_level_start_index (static, hardcoded)
    const float* w_off  = (const float*)d_in[5];
    const float* b_off  = (const float*)d_in[6];
    const float* w_attn = (const float*)d_in[7];
    const float* b_attn = (const float*)d_in[8];
    const float* w_val  = (const float*)d_in[9];
    const float* b_val  = (const float*)d_in[10];
    const float* w_out  = (const float*)d_in[11];
    const float* b_out  = (const float*)d_in[12];
    float* out = (float*)d_out;

    const size_t nr = (size_t)M_ROWS;            // 21760
    float* p = (float*)d_ws;
    float* value_ws = p; p += nr * 256;          // fp32 [M,256]
    float* ol_ws    = p; p += nr * 384;          // fp32 [M,384] = [offv | logits]
    float* tmp_ws   = p; p += nr * 256;          // fp32 [M,256]
    float* bc_ws    = p; p += 384;               // concat bias [b_off | b_attn]
    __half* wv_hi = (__half*)p;                  // weights hi/lo, transposed [NC][256]
    __half* wv_lo = wv_hi + 256 * 256;
    __half* wc_hi = wv_lo + 256 * 256;           // combined [384][256]
    __half* wc_lo = wc_hi + 384 * 256;
    __half* wt_hi = wc_lo + 384 * 256;
    __half* wt_lo = wt_hi + 256 * 256;

    convert_all<<<898, 256, 0, stream>>>(w_val, w_off, w_attn, w_out, b_off, b_attn,
                                         wv_hi, wv_lo, wc_hi, wc_lo, wt_hi, wt_lo, bc_ws);

    dim3 g256(4, M_ROWS / 128);   // (4, 170) = 680 blocks, BN=64
    dim3 g384(3, M_ROWS / 128);   // (3, 170) = 510 blocks, BN=128

    gemm_f16x3<256, 64, 4><<<g256, 256, 0, stream>>>(input_flatten, wv_hi, wv_lo, b_val, value_ws);
    gemm_f16x3<384, 128, 2><<<g384, 256, 0, stream>>>(query, wc_hi, wc_lo, bc_ws, ol_ws);

    sample_kernel<<<M_ROWS / 8, 256, 0, stream>>>(value_ws, ol_ws, refpts, tmp_ws);

    gemm_f16x3<256, 64, 4><<<g256, 256, 0, stream>>>(tmp_ws, wt_hi, wt_lo, b_out, out);
}